// Round 4
// baseline (253.160 us; speedup 1.0000x reference)
//
#include <hip/hip_runtime.h>

// ---------------------------------------------------------------------------
// Fused full attention (V, A). B=4 L=S=2048 H=8 E=64, fp32 in/out.
// Prep (d_ws): Q,K -> bf16 head-major; V -> bf16 transposed [b][h][e][s];
// mask int32 -> bit-packed u64.
// Main: WG = 512 thr = 8 waves = 4 q-subtiles x 2 s-halves. Wave (ws, sh)
// owns q rows qt*64+ws*16..+15 and s-half sh of every 64-s chunk.
//   pass 1: l = sum exp(s-4) over own half; halves summed via LDS.
//   pass 2: A = exp(s-4)/l nt-stores (own half); PV mfma with kc2=sh;
//           accv halves combined via LDS at the end.
// K staged to LDS via global_load_lds w=16 (pre-swizzled source), dbuf,
// 1 barrier/chunk. V read directly from L2 (panel is 256KB, L2-resident).
// Occupancy: 8192 waves total = 32/CU (was 4096 = 16/CU).
// ---------------------------------------------------------------------------

typedef __attribute__((ext_vector_type(8))) short bf16x8;
typedef __attribute__((ext_vector_type(4))) short bf16x4;
typedef __attribute__((ext_vector_type(4))) float f32x4;

#define NB 4
#define NL 2048
#define NS 2048
#define NH 8
#define NE 64
#define TQ 64
#define SKC 64
#define SCALE 0.125f
#define MBIAS 4.0f

static __device__ __forceinline__ short f2bf(float x) {
  unsigned u = __builtin_bit_cast(unsigned, x);
  u += 0x7fffu + ((u >> 16) & 1u);   // round-to-nearest-even
  return (short)(u >> 16);
}

// ---------------- prep kernels ----------------

__global__ __launch_bounds__(256) void cvt_headmajor(const float* __restrict__ in,
                                                     short* __restrict__ out) {
  long i4 = ((long)blockIdx.x * 256 + threadIdx.x) * 4;
  f32x4 v = *(const f32x4*)(in + i4);
  int e4 = (int)(i4 & 63);
  long r = i4 >> 6;
  int h = (int)(r & 7);
  long r2 = r >> 3;
  int t = (int)(r2 & 2047);
  int b = (int)(r2 >> 11);
  bf16x4 o;
  o[0] = f2bf(v[0]); o[1] = f2bf(v[1]); o[2] = f2bf(v[2]); o[3] = f2bf(v[3]);
  *(bf16x4*)(out + ((((long)b * NH + h) * NL + t) * NE + e4)) = o;
}

__global__ __launch_bounds__(256) void transpose_v(const float* __restrict__ V,
                                                   short* __restrict__ Vt) {
  __shared__ short t_lds[64 * 65];
  const int tid = threadIdx.x;
  const int b = blockIdx.x >> 8;
  const int h = (blockIdx.x >> 5) & 7;
  const int sb = (blockIdx.x & 31) * 64;
  {
    const int s = tid >> 2, e0 = (tid & 3) * 16;
    const float* vp = V + ((((long)b * NS + sb + s) * NH + h) * NE + e0);
    #pragma unroll
    for (int j = 0; j < 4; ++j) {
      f32x4 u = *(const f32x4*)(vp + j * 4);
      #pragma unroll
      for (int r = 0; r < 4; ++r) t_lds[(e0 + j * 4 + r) * 65 + s] = f2bf(u[r]);
    }
  }
  __syncthreads();
  {
    const int e = tid >> 2, s0 = (tid & 3) * 16;
    short* op = Vt + (((long)b * NH + h) * NE + e) * NS + sb + s0;
    short tmp[16];
    #pragma unroll
    for (int j = 0; j < 16; ++j) tmp[j] = t_lds[e * 65 + s0 + j];
    *(bf16x8*)(op)     = *(bf16x8*)(tmp);
    *(bf16x8*)(op + 8) = *(bf16x8*)(tmp + 8);
  }
}

__global__ __launch_bounds__(256) void pack_mask(const int* __restrict__ M,
                                                 unsigned long long* __restrict__ Mb) {
  const long total = (long)NB * NL * NS;
  long g = (long)blockIdx.x * 256 + threadIdx.x;
  const long stride = (long)gridDim.x * 256;
  for (; g < total; g += stride) {
    unsigned long long bal = __ballot(M[g] != 0);
    if ((threadIdx.x & 63) == 0) Mb[g >> 6] = bal;
  }
}

// ---------------- main kernel ----------------

// Stage one 64x64 bf16 K chunk with 512 threads (one 16B gload_lds each).
// Linear LDS dest (wave-uniform base + lane*16); swizzle via pre-swizzled
// global source: thread t covers row rr=t>>3, 16B-group gg=(t&7)^(rr&7).
static __device__ __forceinline__ void stage_k(const short* __restrict__ base,
                                               short* lds, int tid) {
  const int rr = tid >> 3;
  const int gg = (tid & 7) ^ (rr & 7);
  const short* sp = base + rr * NE + gg * 8;
  __builtin_amdgcn_global_load_lds(
      (const __attribute__((address_space(1))) void*)sp,
      (__attribute__((address_space(3))) void*)(void*)((char*)lds + (tid >> 6) * 1024),
      16, 0, 0);
}

__global__ __launch_bounds__(512, 8)
void attn_main(const short* __restrict__ Qb, const short* __restrict__ Kb,
               const short* __restrict__ Vt, const unsigned long long* __restrict__ Mb,
               float* __restrict__ OutV, float* __restrict__ OutA)
{
  __shared__ short k_lds[2][SKC * 64];   // 16 KB
  __shared__ short p_lds[8][16 * 64];    // 16 KB (also reused as f32 scratch)

  const int bid = blockIdx.x;
  const int hh = bid & 7, qt = (bid >> 3) & 31, bb = bid >> 8;
  const int tid = threadIdx.x, w = tid >> 6, lane = tid & 63;
  const int ws = w & 3;          // q subtile
  const int sh = w >> 2;         // s half (0: s in [0,32) of chunk, 1: [32,64))
  const int lq = lane & 15, lg = lane >> 4;
  const int qw = qt * TQ + ws * 16, qrow = qw + lq;

  const short* Kpan = Kb + (long)(bb * NH + hh) * NS * NE;
  const short* Vpan = Vt + (long)(bb * NH + hh) * NE * NS;

  bf16x8 qf0, qf1;
  {
    const short* qp = Qb + ((long)(bb * NH + hh) * NL + qrow) * NE + 8 * lg;
    qf0 = *(const bf16x8*)(qp);
    qf1 = *(const bf16x8*)(qp + 32);
  }

  const unsigned long long* mrow = Mb + ((long)bb * NL + qrow) * (NS / 64);

  // ---------------- pass 1: l = sum exp(s - 4) over own s-half ----------------
  float l = 0.f;
  stage_k(Kpan, &k_lds[0][0], tid);
  __syncthreads();
  unsigned long long mcur = mrow[0];
  for (int sb = 0; sb < NS; sb += SKC) {
    const int cb = (sb >> 6) & 1;
    if (sb + SKC < NS) stage_k(Kpan + (long)(sb + SKC) * NE, &k_lds[cb ^ 1][0], tid);
    const unsigned long long mnext = (sb + SKC < NS) ? mrow[(sb >> 6) + 1] : 0ULL;
    #pragma unroll
    for (int st2 = 0; st2 < 32; st2 += 16) {
      const int st = sh * 32 + st2;
      const int krow = st + lq, sw = (krow & 7) << 3;
      const bf16x8 kf0 = *(const bf16x8*)&k_lds[cb][(krow * 64 + 8 * lg) ^ sw];
      const bf16x8 kf1 = *(const bf16x8*)&k_lds[cb][(krow * 64 + 32 + 8 * lg) ^ sw];
      f32x4 c = {0.f, 0.f, 0.f, 0.f};
      c = __builtin_amdgcn_mfma_f32_16x16x32_bf16(kf0, qf0, c, 0, 0, 0);
      c = __builtin_amdgcn_mfma_f32_16x16x32_bf16(kf1, qf1, c, 0, 0, 0);
      const unsigned mb4 = (unsigned)(mcur >> (st + 4 * lg)) & 0xFu;
      l += (mb4 & 1u) ? 0.f : __expf(fmaf(c[0], SCALE, -MBIAS));
      l += (mb4 & 2u) ? 0.f : __expf(fmaf(c[1], SCALE, -MBIAS));
      l += (mb4 & 4u) ? 0.f : __expf(fmaf(c[2], SCALE, -MBIAS));
      l += (mb4 & 8u) ? 0.f : __expf(fmaf(c[3], SCALE, -MBIAS));
    }
    mcur = mnext;
    __syncthreads();
  }
  l += __shfl_xor(l, 16, 64);
  l += __shfl_xor(l, 32, 64);
  // combine the two s-halves via LDS (p_lds as float scratch)
  {
    float* pf32 = (float*)&p_lds[0][0];
    pf32[w * 16 + lq] = l;             // lg lanes write identical value
    __syncthreads();
    l += pf32[(w ^ 4) * 16 + lq];
  }
  const float rinv = 1.0f / l;

  // ---------------- pass 2: A stores + PV (own half) ----------------
  f32x4 accv[4];
  #pragma unroll
  for (int et = 0; et < 4; ++et) accv[et] = (f32x4){0.f, 0.f, 0.f, 0.f};

  float* arow = OutA + (((long)(bb * NH + hh)) * NL + qrow) * NS;

  stage_k(Kpan, &k_lds[0][0], tid);
  __syncthreads();   // also orders the rinv-exchange reads before p_lds reuse
  mcur = mrow[0];
  for (int sb = 0; sb < NS; sb += SKC) {
    const int cb = (sb >> 6) & 1;
    if (sb + SKC < NS) stage_k(Kpan + (long)(sb + SKC) * NE, &k_lds[cb ^ 1][0], tid);
    const unsigned long long mnext = (sb + SKC < NS) ? mrow[(sb >> 6) + 1] : 0ULL;
    #pragma unroll
    for (int st2 = 0; st2 < 32; st2 += 16) {
      const int st = sh * 32 + st2;
      const int krow = st + lq, sw = (krow & 7) << 3;
      const bf16x8 kf0 = *(const bf16x8*)&k_lds[cb][(krow * 64 + 8 * lg) ^ sw];
      const bf16x8 kf1 = *(const bf16x8*)&k_lds[cb][(krow * 64 + 32 + 8 * lg) ^ sw];
      f32x4 c = {0.f, 0.f, 0.f, 0.f};
      c = __builtin_amdgcn_mfma_f32_16x16x32_bf16(kf0, qf0, c, 0, 0, 0);
      c = __builtin_amdgcn_mfma_f32_16x16x32_bf16(kf1, qf1, c, 0, 0, 0);
      const unsigned mb4 = (unsigned)(mcur >> (st + 4 * lg)) & 0xFu;
      const float p0 = (mb4 & 1u) ? 0.f : __expf(fmaf(c[0], SCALE, -MBIAS));
      const float p1 = (mb4 & 2u) ? 0.f : __expf(fmaf(c[1], SCALE, -MBIAS));
      const float p2 = (mb4 & 4u) ? 0.f : __expf(fmaf(c[2], SCALE, -MBIAS));
      const float p3 = (mb4 & 8u) ? 0.f : __expf(fmaf(c[3], SCALE, -MBIAS));
      const float a0 = p0 * rinv, a1 = p1 * rinv, a2 = p2 * rinv, a3 = p3 * rinv;
      f32x4 av = {a0, a1, a2, a3};
      __builtin_nontemporal_store(av, (f32x4*)(arow + sb + st + 4 * lg));
      // normalized P (rinv is for q=qw+lq = this lane's P row)
      bf16x4 pv;
      pv[0] = f2bf(a0); pv[1] = f2bf(a1); pv[2] = f2bf(a2); pv[3] = f2bf(a3);
      *(bf16x4*)&p_lds[w][(lq * 64 + st + 4 * lg) ^ ((lq & 7) << 3)] = pv;
    }
    // PV over own 32-s half (kc2 = sh), V fragments direct from L2
    {
      const bf16x8 pf = *(const bf16x8*)&p_lds[w][(lq * 64 + sh * 32 + 8 * lg) ^ ((lq & 7) << 3)];
      const short* vbase = Vpan + sb + sh * 32 + 8 * lg + (long)lq * NS;
      #pragma unroll
      for (int et = 0; et < 4; ++et) {
        const bf16x8 vf = *(const bf16x8*)(vbase + (long)(et * 16) * NS);
        accv[et] = __builtin_amdgcn_mfma_f32_16x16x32_bf16(pf, vf, accv[et], 0, 0, 0);
      }
    }
    mcur = mnext;
    __syncthreads();
  }

  // combine accv halves: upper waves store to LDS, lower waves add + write V
  {
    float* pf32 = (float*)&p_lds[0][0];   // 4096 floats = 4 waves x 64 lanes x 16
    if (sh == 1) {
      #pragma unroll
      for (int et = 0; et < 4; ++et)
        *(f32x4*)&pf32[((ws * 64 + lane) * 16) + et * 4] = accv[et];
    }
    __syncthreads();
    if (sh == 0) {
      float* vout = OutV + (((long)bb * NL + qw + 4 * lg) * NH + hh) * NE + lq;
      #pragma unroll
      for (int et = 0; et < 4; ++et) {
        const f32x4 other = *(const f32x4*)&pf32[((ws * 64 + lane) * 16) + et * 4];
        #pragma unroll
        for (int r = 0; r < 4; ++r)
          vout[(long)r * (NH * NE) + et * 16] = accv[et][r] + other[r];
      }
    }
  }
}

extern "C" void kernel_launch(void* const* d_in, const int* in_sizes, int n_in,
                              void* d_out, int out_size, void* d_ws, size_t ws_size,
                              hipStream_t stream) {
  const float* Q = (const float*)d_in[0];
  const float* K = (const float*)d_in[1];
  const float* V = (const float*)d_in[2];
  const int*   M = (const int*)d_in[3];
  float* outv = (float*)d_out;
  float* outa = outv + (size_t)NB * NL * NH * NE;

  const size_t NQK = (size_t)NB * NH * NL * NE;
  short* Qb  = (short*)d_ws;
  short* Kbw = Qb + NQK;
  short* Vtw = Kbw + NQK;
  unsigned long long* Mbp = (unsigned long long*)(Vtw + NQK);

  cvt_headmajor<<<dim3((unsigned)(NQK / 4 / 256)), 256, 0, stream>>>(Q, Qb);
  cvt_headmajor<<<dim3((unsigned)(NQK / 4 / 256)), 256, 0, stream>>>(K, Kbw);
  transpose_v<<<dim3(NB * NH * (NS / 64)), 256, 0, stream>>>(V, Vtw);
  pack_mask<<<dim3(2048), 256, 0, stream>>>(M, Mbp);

  attn_main<<<dim3(NB * (NL / TQ) * NH), 512, 0, stream>>>(Qb, Kbw, Vtw, Mbp, outv, outa);
}

// Round 5
// 213.626 us; speedup vs baseline: 1.1851x; 1.1851x over previous
//
#include <hip/hip_runtime.h>

// ---------------------------------------------------------------------------
// Fused full attention (V, A). B=4 L=S=2048 H=8 E=64, fp32 in/out.
// Prep (d_ws): Q,K -> bf16 head-major; V -> bf16 transposed [b][h][e][s];
// mask int32 -> bit-packed u64.
// Main: WG = 256 thr = 4 waves; WG owns TWO 64-row q-tiles (A,B), 3 K-sweeps:
//   sweep1: pass1(A)  (l_A)
//   sweep2: pass2(A) FUSED with pass1(B) — A-stores overlap B-compute,
//           kf LDS reads shared by both QK^T streams.
//   sweep3: pass2(B)
// K (and V in sweeps 2,3) staged via global_load_lds w=16 with pre-swizzled
// source (linear LDS dest), double-buffered, 1 barrier/chunk.
// ---------------------------------------------------------------------------

typedef __attribute__((ext_vector_type(8))) short bf16x8;
typedef __attribute__((ext_vector_type(4))) short bf16x4;
typedef __attribute__((ext_vector_type(4))) float f32x4;

#define NB 4
#define NL 2048
#define NS 2048
#define NH 8
#define NE 64
#define SKC 64
#define SCALE 0.125f
#define MBIAS 4.0f

static __device__ __forceinline__ short f2bf(float x) {
  unsigned u = __builtin_bit_cast(unsigned, x);
  u += 0x7fffu + ((u >> 16) & 1u);   // round-to-nearest-even
  return (short)(u >> 16);
}

// ---------------- prep kernels ----------------

__global__ __launch_bounds__(256) void cvt_headmajor(const float* __restrict__ in,
                                                     short* __restrict__ out) {
  long i4 = ((long)blockIdx.x * 256 + threadIdx.x) * 4;
  f32x4 v = *(const f32x4*)(in + i4);
  int e4 = (int)(i4 & 63);
  long r = i4 >> 6;
  int h = (int)(r & 7);
  long r2 = r >> 3;
  int t = (int)(r2 & 2047);
  int b = (int)(r2 >> 11);
  bf16x4 o;
  o[0] = f2bf(v[0]); o[1] = f2bf(v[1]); o[2] = f2bf(v[2]); o[3] = f2bf(v[3]);
  *(bf16x4*)(out + ((((long)b * NH + h) * NL + t) * NE + e4)) = o;
}

__global__ __launch_bounds__(256) void transpose_v(const float* __restrict__ V,
                                                   short* __restrict__ Vt) {
  __shared__ short t_lds[64 * 65];
  const int tid = threadIdx.x;
  const int b = blockIdx.x >> 8;
  const int h = (blockIdx.x >> 5) & 7;
  const int sb = (blockIdx.x & 31) * 64;
  {
    const int s = tid >> 2, e0 = (tid & 3) * 16;
    const float* vp = V + ((((long)b * NS + sb + s) * NH + h) * NE + e0);
    #pragma unroll
    for (int j = 0; j < 4; ++j) {
      f32x4 u = *(const f32x4*)(vp + j * 4);
      #pragma unroll
      for (int r = 0; r < 4; ++r) t_lds[(e0 + j * 4 + r) * 65 + s] = f2bf(u[r]);
    }
  }
  __syncthreads();
  {
    const int e = tid >> 2, s0 = (tid & 3) * 16;
    short* op = Vt + (((long)b * NH + h) * NE + e) * NS + sb + s0;
    short tmp[16];
    #pragma unroll
    for (int j = 0; j < 16; ++j) tmp[j] = t_lds[e * 65 + s0 + j];
    *(bf16x8*)(op)     = *(bf16x8*)(tmp);
    *(bf16x8*)(op + 8) = *(bf16x8*)(tmp + 8);
  }
}

__global__ __launch_bounds__(256) void pack_mask(const int* __restrict__ M,
                                                 unsigned long long* __restrict__ Mb) {
  const long total = (long)NB * NL * NS;
  long g = (long)blockIdx.x * 256 + threadIdx.x;
  const long stride = (long)gridDim.x * 256;
  for (; g < total; g += stride) {
    unsigned long long bal = __ballot(M[g] != 0);
    if ((threadIdx.x & 63) == 0) Mb[g >> 6] = bal;
  }
}

// ---------------- main kernel ----------------

// Stage a 64-row x 64-elem bf16 tile into LDS (2 gload_lds calls / thread).
// Linear LDS dest; swizzle via pre-swizzled global source.
template<int RS>
static __device__ __forceinline__ void stage_tile(const short* __restrict__ base,
                                                  short* lds, int tid, int w) {
  #pragma unroll
  for (int c = 0; c < 2; ++c) {
    const int rr = (tid >> 3) + c * 32;
    const int gg = (tid & 7) ^ (rr & 7);
    const short* sp = base + (long)rr * RS + gg * 8;
    __builtin_amdgcn_global_load_lds(
        (const __attribute__((address_space(1))) void*)sp,
        (__attribute__((address_space(3))) void*)(void*)((char*)lds + c * 4096 + w * 1024),
        16, 0, 0);
  }
}

__global__ __launch_bounds__(256, 2)
void attn_main(const short* __restrict__ Qb, const short* __restrict__ Kb,
               const short* __restrict__ Vt, const unsigned long long* __restrict__ Mb,
               float* __restrict__ OutV, float* __restrict__ OutA)
{
  __shared__ short k_lds[2][SKC * 64];   // 16 KB
  __shared__ short vt_lds[2][NE * 64];   // 16 KB
  __shared__ short p_lds[4][16 * 64];    // 8 KB

  const int bid = blockIdx.x;
  const int hh = bid & 7, qt = (bid >> 3) & 15, bb = bid >> 7;
  const int tid = threadIdx.x, w = tid >> 6, lane = tid & 63;
  const int lq = lane & 15, lg = lane >> 4;
  const int qwA = qt * 128 + w * 16, qrowA = qwA + lq;
  const int qwB = qwA + 64,          qrowB = qrowA + 64;

  const short* Kpan = Kb + (long)(bb * NH + hh) * NS * NE;
  const short* Vpan = Vt + (long)(bb * NH + hh) * NE * NS;

  bf16x8 qfA0, qfA1, qfB0, qfB1;
  {
    const short* qp = Qb + ((long)(bb * NH + hh) * NL + qrowA) * NE + 8 * lg;
    qfA0 = *(const bf16x8*)(qp);
    qfA1 = *(const bf16x8*)(qp + 32);
    qfB0 = *(const bf16x8*)(qp + 64 * NE);
    qfB1 = *(const bf16x8*)(qp + 64 * NE + 32);
  }

  const unsigned long long* mrowA = Mb + ((long)bb * NL + qrowA) * (NS / 64);
  const unsigned long long* mrowB = Mb + ((long)bb * NL + qrowB) * (NS / 64);

  // ================ sweep 1: pass1(A) — l_A ================
  float l0 = 0.f, l1 = 0.f, l2 = 0.f, l3 = 0.f;
  stage_tile<NE>(Kpan, &k_lds[0][0], tid, w);
  __syncthreads();
  unsigned long long mcA = mrowA[0];
  for (int sb = 0; sb < NS; sb += SKC) {
    const int cb = (sb >> 6) & 1;
    if (sb + SKC < NS)
      stage_tile<NE>(Kpan + (long)(sb + SKC) * NE, &k_lds[cb ^ 1][0], tid, w);
    const unsigned long long mnA = (sb + SKC < NS) ? mrowA[(sb >> 6) + 1] : 0ULL;
    #pragma unroll
    for (int st = 0; st < SKC; st += 16) {
      const int krow = st + lq, sw = (krow & 7) << 3;
      const bf16x8 kf0 = *(const bf16x8*)&k_lds[cb][(krow * 64 + 8 * lg) ^ sw];
      const bf16x8 kf1 = *(const bf16x8*)&k_lds[cb][(krow * 64 + 32 + 8 * lg) ^ sw];
      f32x4 c = {0.f, 0.f, 0.f, 0.f};
      c = __builtin_amdgcn_mfma_f32_16x16x32_bf16(kf0, qfA0, c, 0, 0, 0);
      c = __builtin_amdgcn_mfma_f32_16x16x32_bf16(kf1, qfA1, c, 0, 0, 0);
      const unsigned mb4 = (unsigned)(mcA >> (st + 4 * lg)) & 0xFu;
      l0 += (mb4 & 1u) ? 0.f : __expf(fmaf(c[0], SCALE, -MBIAS));
      l1 += (mb4 & 2u) ? 0.f : __expf(fmaf(c[1], SCALE, -MBIAS));
      l2 += (mb4 & 4u) ? 0.f : __expf(fmaf(c[2], SCALE, -MBIAS));
      l3 += (mb4 & 8u) ? 0.f : __expf(fmaf(c[3], SCALE, -MBIAS));
    }
    mcA = mnA;
    __syncthreads();
  }
  float lA = (l0 + l1) + (l2 + l3);
  lA += __shfl_xor(lA, 16, 64);
  lA += __shfl_xor(lA, 32, 64);
  const float rinvA = 1.0f / lA;

  // ================ sweep 2: pass2(A) fused with pass1(B) ================
  f32x4 accvA[4];
  #pragma unroll
  for (int et = 0; et < 4; ++et) accvA[et] = (f32x4){0.f, 0.f, 0.f, 0.f};
  l0 = l1 = l2 = l3 = 0.f;   // now accumulate l_B

  float* arowA = OutA + (((long)(bb * NH + hh)) * NL + qrowA) * NS;

  stage_tile<NE>(Kpan, &k_lds[0][0], tid, w);
  stage_tile<NS>(Vpan, &vt_lds[0][0], tid, w);
  __syncthreads();
  mcA = mrowA[0];
  unsigned long long mcB = mrowB[0];
  for (int sb = 0; sb < NS; sb += SKC) {
    const int cb = (sb >> 6) & 1;
    if (sb + SKC < NS) {
      stage_tile<NE>(Kpan + (long)(sb + SKC) * NE, &k_lds[cb ^ 1][0], tid, w);
      stage_tile<NS>(Vpan + (sb + SKC), &vt_lds[cb ^ 1][0], tid, w);
    }
    const unsigned long long mnA = (sb + SKC < NS) ? mrowA[(sb >> 6) + 1] : 0ULL;
    const unsigned long long mnB = (sb + SKC < NS) ? mrowB[(sb >> 6) + 1] : 0ULL;
    #pragma unroll
    for (int st = 0; st < SKC; st += 16) {
      const int krow = st + lq, sw = (krow & 7) << 3;
      const bf16x8 kf0 = *(const bf16x8*)&k_lds[cb][(krow * 64 + 8 * lg) ^ sw];
      const bf16x8 kf1 = *(const bf16x8*)&k_lds[cb][(krow * 64 + 32 + 8 * lg) ^ sw];
      // tile A: recompute scores -> A stores + P tile (kf shared with B)
      f32x4 cA = {0.f, 0.f, 0.f, 0.f};
      cA = __builtin_amdgcn_mfma_f32_16x16x32_bf16(kf0, qfA0, cA, 0, 0, 0);
      cA = __builtin_amdgcn_mfma_f32_16x16x32_bf16(kf1, qfA1, cA, 0, 0, 0);
      // tile B: first-pass scores -> l_B
      f32x4 cB = {0.f, 0.f, 0.f, 0.f};
      cB = __builtin_amdgcn_mfma_f32_16x16x32_bf16(kf0, qfB0, cB, 0, 0, 0);
      cB = __builtin_amdgcn_mfma_f32_16x16x32_bf16(kf1, qfB1, cB, 0, 0, 0);
      const unsigned mA4 = (unsigned)(mcA >> (st + 4 * lg)) & 0xFu;
      const float p0 = (mA4 & 1u) ? 0.f : __expf(fmaf(cA[0], SCALE, -MBIAS));
      const float p1 = (mA4 & 2u) ? 0.f : __expf(fmaf(cA[1], SCALE, -MBIAS));
      const float p2 = (mA4 & 4u) ? 0.f : __expf(fmaf(cA[2], SCALE, -MBIAS));
      const float p3 = (mA4 & 8u) ? 0.f : __expf(fmaf(cA[3], SCALE, -MBIAS));
      const float a0 = p0 * rinvA, a1 = p1 * rinvA, a2 = p2 * rinvA, a3 = p3 * rinvA;
      f32x4 av = {a0, a1, a2, a3};
      __builtin_nontemporal_store(av, (f32x4*)(arowA + sb + st + 4 * lg));
      bf16x4 pv;
      pv[0] = f2bf(a0); pv[1] = f2bf(a1); pv[2] = f2bf(a2); pv[3] = f2bf(a3);
      *(bf16x4*)&p_lds[w][(lq * 64 + st + 4 * lg) ^ ((lq & 7) << 3)] = pv;
      const unsigned mB4 = (unsigned)(mcB >> (st + 4 * lg)) & 0xFu;
      l0 += (mB4 & 1u) ? 0.f : __expf(fmaf(cB[0], SCALE, -MBIAS));
      l1 += (mB4 & 2u) ? 0.f : __expf(fmaf(cB[1], SCALE, -MBIAS));
      l2 += (mB4 & 4u) ? 0.f : __expf(fmaf(cB[2], SCALE, -MBIAS));
      l3 += (mB4 & 8u) ? 0.f : __expf(fmaf(cB[3], SCALE, -MBIAS));
    }
    // PV(A) over this 64-s chunk
    #pragma unroll
    for (int kc2 = 0; kc2 < 2; ++kc2) {
      const bf16x8 pf = *(const bf16x8*)&p_lds[w][(lq * 64 + kc2 * 32 + 8 * lg) ^ ((lq & 7) << 3)];
      #pragma unroll
      for (int et = 0; et < 4; ++et) {
        const int er = et * 16 + lq;
        const bf16x8 vf = *(const bf16x8*)&vt_lds[cb][(er * 64 + kc2 * 32 + 8 * lg) ^ ((er & 7) << 3)];
        accvA[et] = __builtin_amdgcn_mfma_f32_16x16x32_bf16(pf, vf, accvA[et], 0, 0, 0);
      }
    }
    mcA = mnA; mcB = mnB;
    __syncthreads();
  }
  float lB = (l0 + l1) + (l2 + l3);
  lB += __shfl_xor(lB, 16, 64);
  lB += __shfl_xor(lB, 32, 64);
  const float rinvB = 1.0f / lB;

  // write V(A): lane holds out[q = qwA + 4*lg + r][e = et*16 + lq]
  {
    float* vout = OutV + (((long)bb * NL + qwA + 4 * lg) * NH + hh) * NE + lq;
    #pragma unroll
    for (int r = 0; r < 4; ++r)
      #pragma unroll
      for (int et = 0; et < 4; ++et)
        vout[(long)r * (NH * NE) + et * 16] = accvA[et][r];
  }

  // ================ sweep 3: pass2(B) ================
  f32x4 accvB[4];
  #pragma unroll
  for (int et = 0; et < 4; ++et) accvB[et] = (f32x4){0.f, 0.f, 0.f, 0.f};

  float* arowB = OutA + (((long)(bb * NH + hh)) * NL + qrowB) * NS;

  stage_tile<NE>(Kpan, &k_lds[0][0], tid, w);
  stage_tile<NS>(Vpan, &vt_lds[0][0], tid, w);
  __syncthreads();
  mcB = mrowB[0];
  for (int sb = 0; sb < NS; sb += SKC) {
    const int cb = (sb >> 6) & 1;
    if (sb + SKC < NS) {
      stage_tile<NE>(Kpan + (long)(sb + SKC) * NE, &k_lds[cb ^ 1][0], tid, w);
      stage_tile<NS>(Vpan + (sb + SKC), &vt_lds[cb ^ 1][0], tid, w);
    }
    const unsigned long long mnB = (sb + SKC < NS) ? mrowB[(sb >> 6) + 1] : 0ULL;
    #pragma unroll
    for (int st = 0; st < SKC; st += 16) {
      const int krow = st + lq, sw = (krow & 7) << 3;
      const bf16x8 kf0 = *(const bf16x8*)&k_lds[cb][(krow * 64 + 8 * lg) ^ sw];
      const bf16x8 kf1 = *(const bf16x8*)&k_lds[cb][(krow * 64 + 32 + 8 * lg) ^ sw];
      f32x4 c = {0.f, 0.f, 0.f, 0.f};
      c = __builtin_amdgcn_mfma_f32_16x16x32_bf16(kf0, qfB0, c, 0, 0, 0);
      c = __builtin_amdgcn_mfma_f32_16x16x32_bf16(kf1, qfB1, c, 0, 0, 0);
      const unsigned mb4 = (unsigned)(mcB >> (st + 4 * lg)) & 0xFu;
      const float p0 = (mb4 & 1u) ? 0.f : __expf(fmaf(c[0], SCALE, -MBIAS));
      const float p1 = (mb4 & 2u) ? 0.f : __expf(fmaf(c[1], SCALE, -MBIAS));
      const float p2 = (mb4 & 4u) ? 0.f : __expf(fmaf(c[2], SCALE, -MBIAS));
      const float p3 = (mb4 & 8u) ? 0.f : __expf(fmaf(c[3], SCALE, -MBIAS));
      const float a0 = p0 * rinvB, a1 = p1 * rinvB, a2 = p2 * rinvB, a3 = p3 * rinvB;
      f32x4 av = {a0, a1, a2, a3};
      __builtin_nontemporal_store(av, (f32x4*)(arowB + sb + st + 4 * lg));
      bf16x4 pv;
      pv[0] = f2bf(a0); pv[1] = f2bf(a1); pv[2] = f2bf(a2); pv[3] = f2bf(a3);
      *(bf16x4*)&p_lds[w][(lq * 64 + st + 4 * lg) ^ ((lq & 7) << 3)] = pv;
    }
    #pragma unroll
    for (int kc2 = 0; kc2 < 2; ++kc2) {
      const bf16x8 pf = *(const bf16x8*)&p_lds[w][(lq * 64 + kc2 * 32 + 8 * lg) ^ ((lq & 7) << 3)];
      #pragma unroll
      for (int et = 0; et < 4; ++et) {
        const int er = et * 16 + lq;
        const bf16x8 vf = *(const bf16x8*)&vt_lds[cb][(er * 64 + kc2 * 32 + 8 * lg) ^ ((er & 7) << 3)];
        accvB[et] = __builtin_amdgcn_mfma_f32_16x16x32_bf16(pf, vf, accvB[et], 0, 0, 0);
      }
    }
    mcB = mnB;
    __syncthreads();
  }

  // write V(B)
  {
    float* vout = OutV + (((long)bb * NL + qwB + 4 * lg) * NH + hh) * NE + lq;
    #pragma unroll
    for (int r = 0; r < 4; ++r)
      #pragma unroll
      for (int et = 0; et < 4; ++et)
        vout[(long)r * (NH * NE) + et * 16] = accvB[et][r];
  }
}

extern "C" void kernel_launch(void* const* d_in, const int* in_sizes, int n_in,
                              void* d_out, int out_size, void* d_ws, size_t ws_size,
                              hipStream_t stream) {
  const float* Q = (const float*)d_in[0];
  const float* K = (const float*)d_in[1];
  const float* V = (const float*)d_in[2];
  const int*   M = (const int*)d_in[3];
  float* outv = (float*)d_out;
  float* outa = outv + (size_t)NB * NL * NH * NE;

  const size_t NQK = (size_t)NB * NH * NL * NE;
  short* Qb  = (short*)d_ws;
  short* Kbw = Qb + NQK;
  short* Vtw = Kbw + NQK;
  unsigned long long* Mbp = (unsigned long long*)(Vtw + NQK);

  cvt_headmajor<<<dim3((unsigned)(NQK / 4 / 256)), 256, 0, stream>>>(Q, Qb);
  cvt_headmajor<<<dim3((unsigned)(NQK / 4 / 256)), 256, 0, stream>>>(K, Kbw);
  transpose_v<<<dim3(NB * NH * (NS / 64)), 256, 0, stream>>>(V, Vtw);
  pack_mask<<<dim3(2048), 256, 0, stream>>>(M, Mbp);

  attn_main<<<dim3(NB * (NL / 128) * NH), 256, 0, stream>>>(Qb, Kbw, Vtw, Mbp, outv, outa);
}